// Round 11
// baseline (1455.540 us; speedup 1.0000x reference)
//
#include <hip/hip_runtime.h>
#include <hip/hip_bf16.h>

// Problem constants (from reference)
constexpr int BB = 16;     // batches
constexpr int NN = 8192;   // points
constexpr int SS = 1024;   // samples (FPS)
constexpr int KK = 32;     // kNN
constexpr int BUFC = 256;  // per-wave candidate buffer (keys <= That)
constexpr int NWORKW = 240 * 8;   // worker waves (blocks 16..255, 8 waves each)

__device__ __forceinline__ float b2f(__hip_bfloat16 h) { return __bfloat162float(h); }

// Monotone map f32 -> u32 (order-preserving, bijective; d is never -0 here).
__device__ __forceinline__ unsigned mkey32(float d) {
    unsigned u = __float_as_uint(d);
    return u ^ (0x80000000u | (unsigned)((int)u >> 31));
}

// Deterministic distance key for point idx vs query (qx,qy,qz,qq).
// Same expression sequence every call -> bit-identical results (IEEE, no FMA).
__device__ __forceinline__ unsigned long long dist_key(const float* __restrict__ pb,
                                                       int idx, float qx, float qy,
                                                       float qz, float qq) {
    float px = pb[idx * 3 + 0];
    float py = pb[idx * 3 + 1];
    float pz = pb[idx * 3 + 2];
    float dot = __fadd_rn(__fadd_rn(__fmul_rn(qx, px), __fmul_rn(qy, py)), __fmul_rn(qz, pz));
    float pp  = __fadd_rn(__fadd_rn(__fmul_rn(px, px), __fmul_rn(py, py)), __fmul_rn(pz, pz));
    float d = __fadd_rn(__fadd_rn(__fmul_rn(-2.0f, dot), qq), pp);
    return ((unsigned long long)mkey32(d) << 32) | (unsigned)idx;
}

// DPP lane-move of a u64 (both halves move identically).
template <int CTRL, int RMASK>
__device__ __forceinline__ unsigned long long dppmove_u64(unsigned long long v) {
    int lo = (int)(unsigned)v, hi = (int)(unsigned)(v >> 32);
    int nlo = __builtin_amdgcn_update_dpp(lo, lo, CTRL, RMASK, 0xf, false);
    int nhi = __builtin_amdgcn_update_dpp(hi, hi, CTRL, RMASK, 0xf, false);
    return ((unsigned long long)(unsigned)nhi << 32) | (unsigned)nlo;
}

// FPS keys are (dist_bits<<32)|~idx -> positive finite f64; bit order ==
// numeric order -> v_max_f64 replaces cmp+2*cndmask in every reduce stage.
template <int CTRL, int RMASK>
__device__ __forceinline__ double dppmax_f64(double v) {
    double m = __longlong_as_double(
        dppmove_u64<CTRL, RMASK>((unsigned long long)__double_as_longlong(v)));
    return fmax(v, m);
}

// Wave64 max-reduce via DPP. Lane 63 holds the max.
__device__ __forceinline__ double wave_max_dpp_f64(double v) {
    v = dppmax_f64<0x121, 0xf>(v);  // row_ror:1
    v = dppmax_f64<0x122, 0xf>(v);  // row_ror:2
    v = dppmax_f64<0x124, 0xf>(v);  // row_ror:4
    v = dppmax_f64<0x128, 0xf>(v);  // row_ror:8
    v = dppmax_f64<0x142, 0xa>(v);  // row_bcast:15 -> rows 1,3
    v = dppmax_f64<0x143, 0xc>(v);  // row_bcast:31 -> rows 2,3
    return v;
}

// Cross-lane bitonic sort of 64 u64 keys (ascending); lane i ends with i-th smallest.
__device__ __forceinline__ unsigned long long bitonic64(unsigned long long v, int lane) {
#pragma unroll
    for (int k = 2; k <= 64; k <<= 1) {
#pragma unroll
        for (int j = k >> 1; j > 0; j >>= 1) {
            unsigned long long p = __shfl_xor(v, j);
            bool up = ((lane & k) == 0);
            bool lower = ((lane & j) == 0);
            bool take_min = (up == lower);
            v = take_min ? (p < v ? p : v) : (p > v ? p : v);
        }
    }
    return v;
}

// 10-bit -> every-3rd-bit expansion (Morton interleave helper).
__device__ __forceinline__ unsigned expand3(unsigned v) {
    v &= 0x3FFu;
    v = (v | (v << 16)) & 0x030000FFu;
    v = (v | (v << 8))  & 0x0300F00Fu;
    v = (v | (v << 4))  & 0x030C30C3u;
    v = (v | (v << 2))  & 0x09249249u;
    return v;
}

// ---------------------------------------------------------------------------
// knn for ONE query (b,s), one wave. Bit-identical to the r14-r24 standalone
// kernel (RECOMPUTE form: pass 1 lane-min only; pass 2 recomputes keys; no
// per-lane key array -> no scratch). buf = 256-slot u64 LDS region per wave.
// ---------------------------------------------------------------------------
__device__ void knn_query(const float* __restrict__ xyzf,
                          const float* __restrict__ new_xyz,
                          float* __restrict__ A, double* __restrict__ qstats,
                          int b, int s, int lane,
                          unsigned long long* __restrict__ buf) {
    const int w = (b << 10) | s;
    const float* q = new_xyz + ((size_t)b * SS + s) * 3;
    float qx = q[0], qy = q[1], qz = q[2];
    float qq = __fadd_rn(__fadd_rn(__fmul_rn(qx, qx), __fmul_rn(qy, qy)), __fmul_rn(qz, qz));

    const float* pb = xyzf + (size_t)b * NN * 3;
    const unsigned long long ltmask = (1ull << lane) - 1ull;

    // pass 1: lane-min key only (no storage)
    unsigned long long lmin = ~0ull;
    for (int j = 0; j < 128; j++) {
        unsigned long long key = dist_key(pb, j * 64 + lane, qx, qy, qz, qq);
        lmin = key < lmin ? key : lmin;
    }

    unsigned long long vs = bitonic64(lmin, lane);
    unsigned long long That = __shfl(vs, 31);

    // pass 2: recompute keys, compact keys <= That into LDS
    for (int i = lane; i < BUFC; i += 64) buf[i] = ~0ull;
    int base = 0;
    for (int j = 0; j < 128; j++) {
        unsigned long long key = dist_key(pb, j * 64 + lane, qx, qy, qz, qq);
        bool f = key <= That;
        unsigned long long bal = __ballot(f);
        int pos = base + __popcll(bal & ltmask);
        if (f && pos < BUFC) buf[pos] = key;
        base += __popcll(bal);
    }

    // rare recovery: tighten threshold (recompute inside search)
    if (base > BUFC) {
        unsigned lo = 0, hi = (unsigned)(That >> 32);
        for (int it = 0; it < 32; it++) {
            unsigned mid = lo + ((hi - lo) >> 1);
            int c = 0;
            for (int j = 0; j < 128; j++) {
                unsigned long long key = dist_key(pb, j * 64 + lane, qx, qy, qz, qq);
                c += ((unsigned)(key >> 32) <= mid) ? 1 : 0;
            }
#pragma unroll
            for (int o = 32; o > 0; o >>= 1) c += __shfl_xor(c, o);
            if (c >= 32) hi = mid; else lo = mid + 1;
        }
        That = ((unsigned long long)hi << 32) | 0xFFFFFFFFull;
        for (int i = lane; i < BUFC; i += 64) buf[i] = ~0ull;
        base = 0;
        for (int j = 0; j < 128; j++) {
            unsigned long long key = dist_key(pb, j * 64 + lane, qx, qy, qz, qq);
            bool f = key <= That;
            unsigned long long bal = __ballot(f);
            int pos = base + __popcll(bal & ltmask);
            if (f && pos < BUFC) buf[pos] = key;
            base += __popcll(bal);
        }
        if (base > BUFC) base = BUFC;
    }

    int M = base;
    unsigned long long kept = ~0ull;
    if (M <= 64) {
        unsigned long long v = (lane < M) ? buf[lane] : ~0ull;
        v = bitonic64(v, lane);
        kept = v;
    } else {
        unsigned long long c0 = buf[lane];
        unsigned long long c1 = buf[64 + lane];
        unsigned long long c2 = buf[128 + lane];
        unsigned long long c3 = buf[192 + lane];
        for (int r = 0; r < KK; r++) {
            unsigned long long m01 = c0 < c1 ? c0 : c1;
            unsigned long long m23 = c2 < c3 ? c2 : c3;
            unsigned long long mm = m01 < m23 ? m01 : m23;
#pragma unroll
            for (int o = 32; o > 0; o >>= 1) {
                unsigned long long t2 = __shfl_xor(mm, o);
                mm = t2 < mm ? t2 : mm;
            }
            if (lane == r) kept = mm;
            c0 = (c0 == mm) ? ~0ull : c0;
            c1 = (c1 == mm) ? ~0ull : c1;
            c2 = (c2 == mm) ? ~0ull : c2;
            c3 = (c3 == mm) ? ~0ull : c3;
        }
    }

    bool act = (lane < KK);
    float gx = 0.0f, gy = 0.0f, gz = 0.0f;
    if (act) {
        unsigned nidx = (unsigned)kept;
        gx = pb[nidx * 3 + 0];
        gy = pb[nidx * 3 + 1];
        gz = pb[nidx * 3 + 2];
    }
    float dx = __fsub_rn(gx, qx);
    float dy = __fsub_rn(gy, qy);
    float dz = __fsub_rn(gz, qz);
    float mx = act ? dx : -3.402823466e38f;
    float my = act ? dy : -3.402823466e38f;
    float mz = act ? dz : -3.402823466e38f;
    float sx = act ? dx : 0.0f;
    float sy = act ? dy : 0.0f;
    float sz = act ? dz : 0.0f;
    double s1 = act ? ((double)dx + (double)dy + (double)dz) : 0.0;
    double s2 = act ? ((double)dx * dx + (double)dy * dy + (double)dz * dz) : 0.0;
#pragma unroll
    for (int o = 32; o > 0; o >>= 1) {
        mx = fmaxf(mx, __shfl_xor(mx, o));
        my = fmaxf(my, __shfl_xor(my, o));
        mz = fmaxf(mz, __shfl_xor(mz, o));
        sx += __shfl_xor(sx, o);
        sy += __shfl_xor(sy, o);
        sz += __shfl_xor(sz, o);
        s1 += __shfl_xor(s1, o);
        s2 += __shfl_xor(s2, o);
    }
    if (lane == 0) {
        float* a = A + ((size_t)b * SS + s) * 3;
        a[0] = __fadd_rn(mx, __fmul_rn(sx, 0.03125f));
        a[1] = __fadd_rn(my, __fmul_rn(sy, 0.03125f));
        a[2] = __fadd_rn(mz, __fmul_rn(sz, 0.03125f));
        qstats[2 * w + 0] = s1;
        qstats[2 * w + 1] = s2;
    }
}

// ---------------------------------------------------------------------------
// K1 (r25): FUSED convert + FPS + STREAMING-kNN workers.
//
// r24 ledger: fps-with-heat 954, tail 151 (knn ~110 of it). The 240 heater
// CUs burned 950us of FMA producing nothing while knn waited. r25: heater
// blocks BECOME knn workers. fps blocks publish each centroid to global
// new_xyz (+~26us, the exact r17-measured cost) + a release-store progress
// beacon every 64 steps; 1920 worker waves sleep-poll (s_sleep, near-zero
// power; fps unthrottled) until their query's sample is ready, run the
// bit-identical knn routine, then FMA-heat until all queries done (warms
// the lc/cdist tail). Stragglers at fps end: only ~63 samples/batch
// unpublished -> ~1008 queries on 1008 distinct waves -> one ~10us burst.
//
// r14's "knn fusion loses" is addressed: workers on DIFFERENT CUs than fps,
// sleeping polls (no bw burn), publish cost known/accepted. Sync = release
// store / acquire load, device scope — the exact pattern r24's cdist ticket
// validated on HW (absmax identical).
//
// fps math = r18 chain, untouched. Selection bit-exact; knn bit-exact.
//
// Carried lessons: waves_per_eu(2,2) pins 256-reg budget (r5/r6); multi-CU
// FPS loses (r8/r9); per-step global store costs ~26us (r17, now accepted);
// issue-work cuts don't move fps (r15/r18); 2-batch state spills/can't cut
// wall (r19/r20); heater intensity curve, optimum=full FMA (r21/r22/r23).
// ---------------------------------------------------------------------------
__global__ __attribute__((amdgpu_flat_work_group_size(512, 512)))
__attribute__((amdgpu_waves_per_eu(2, 2)))
void fps_kernel(const void* __restrict__ xyz_raw, const void* __restrict__ g1r,
                const void* __restrict__ b1r, const void* __restrict__ g2r,
                const void* __restrict__ b2r, float* __restrict__ xyzf,
                float* __restrict__ new_xyz, float* __restrict__ params,
                void* __restrict__ out_raw, int* __restrict__ ctrl,
                float* __restrict__ A, double* __restrict__ qstats) {
    // ctrl[0..15] = per-batch publish count (steps+1); ctrl[16] = queries done
    __shared__ float sxyz[NN * 3];      // fps: coord table; workers: knn buf
    __shared__ unsigned sortk[NN];      // fps: sort keys
    __shared__ double skey[2][8];
    __shared__ float sred[6][8];
    __shared__ float sbb[6];

    // dtype detection (all blocks; same data -> same result)
    const unsigned short* u = (const unsigned short*)xyz_raw;
    unsigned short sdet = u[2 * (threadIdx.x & 63)];
    int e = (sdet >> 7) & 0xFF;
    unsigned long long mball = __ballot(e >= 100 && e <= 140);
    const bool isbf = __popcll(mball) > 48;

    if (blockIdx.x >= 16) {
        // block 16: params conversion + d_out sentinel (one-time, ~1us)
        if (blockIdx.x == 16) {
            int t = threadIdx.x;
            if (t < 85) {
                if (t == 84) {
                    params[84] = isbf ? 1.0f : 0.0f;
                } else {
                    const void* src; int off;
                    if (t < 6)       { src = g1r; off = t; }
                    else if (t < 12) { src = b1r; off = t - 6; }
                    else if (t < 48) { src = g2r; off = t - 12; }
                    else             { src = b2r; off = t - 48; }
                    params[t] = isbf ? b2f(((const __hip_bfloat16*)src)[off])
                                     : ((const float*)src)[off];
                }
            }
            if (t >= 128 && t < 192) {
                for (int i = t - 128; i < 576; i += 64) {
                    if (isbf) ((__hip_bfloat16*)out_raw)[i] = __float2bfloat16(1.0f);
                    else      ((float*)out_raw)[i] = 1.0f;
                }
            }
        }

        // -------- streaming knn worker: wave gw handles q = gw + k*1920,
        // q -> s = q>>4 (monotone in k), b = q&15.
        const int wv = threadIdx.x >> 6, lane = threadIdx.x & 63;
        const int gw = (blockIdx.x - 16) * 8 + wv;
        unsigned long long* mybuf = (unsigned long long*)sxyz + (size_t)wv * BUFC;

        for (int q = gw; q < BB * SS; q += NWORKW) {
            const int s = q >> 4, b = q & 15;
            // sleep-poll until sample s of batch b is published (acquire)
            for (int p = 0; p < 300000; ++p) {
                int pr = __hip_atomic_load(ctrl + b, __ATOMIC_ACQUIRE,
                                           __HIP_MEMORY_SCOPE_AGENT);
                if (pr >= s + 1) break;
                __builtin_amdgcn_s_sleep(64);   // ~4k cycles, near-zero power
            }
            knn_query(xyzf, new_xyz, A, qstats, b, s, lane, mybuf);
            if (lane == 0)
                __hip_atomic_fetch_add(ctrl + 16, 1, __ATOMIC_RELAXED,
                                       __HIP_MEMORY_SCOPE_AGENT);
        }

        // -------- end-phase heat: warm the DPM state into lc/cdist while
        // straggler queries finish (r21 heater body).
        float a0 = 1.0f + threadIdx.x * 1e-7f, a1 = 1.1f, a2 = 1.2f, a3 = 1.3f;
        const float mql = 1.0000001f, cdl = 1e-9f;
        for (int it = 0; it < 20000; ++it) {
#pragma unroll
            for (int k = 0; k < 16; ++k) {
                a0 = __fmaf_rn(a0, mql, cdl);
                a1 = __fmaf_rn(a1, mql, cdl);
                a2 = __fmaf_rn(a2, mql, cdl);
                a3 = __fmaf_rn(a3, mql, cdl);
            }
            if ((it & 7) == 0) {
                int d = __hip_atomic_load(ctrl + 16, __ATOMIC_RELAXED,
                                          __HIP_MEMORY_SCOPE_AGENT);
                if (d >= BB * SS) break;
            }
        }
        asm volatile("" :: "v"(a0), "v"(a1), "v"(a2), "v"(a3));
        return;
    }

    constexpr int T = 512, P = NN / T;  // 16 contiguous sorted points per thread
    const int b = blockIdx.x, t = threadIdx.x;

    // --- inline convert: raw -> f32 -> xyzf (for knn) + sxyz (LDS stage) ---
    {
        float* xout = xyzf + (size_t)b * NN * 3;
        if (isbf) {
            const __hip_bfloat16* p = (const __hip_bfloat16*)xyz_raw + (size_t)b * NN * 3;
            for (int i = t; i < NN * 3; i += T) {
                float v = b2f(p[i]);    // exact widening, same bits as before
                xout[i] = v;
                sxyz[i] = v;
            }
        } else {
            const float* p = (const float*)xyz_raw + (size_t)b * NN * 3;
            for (int i = t; i < NN * 3; i += T) {
                float v = p[i];
                xout[i] = v;
                sxyz[i] = v;
            }
        }
    }
    __syncthreads();

    // --- batch bbox (min/max per axis) for Morton quantization ---
    {
        float mn[3] = {3.4e38f, 3.4e38f, 3.4e38f};
        float mx[3] = {-3.4e38f, -3.4e38f, -3.4e38f};
        for (int j = 0; j < P; j++) {
            int p = t + j * T;
#pragma unroll
            for (int c = 0; c < 3; c++) {
                float v = sxyz[p * 3 + c];
                mn[c] = fminf(mn[c], v);
                mx[c] = fmaxf(mx[c], v);
            }
        }
#pragma unroll
        for (int o = 32; o > 0; o >>= 1) {
#pragma unroll
            for (int c = 0; c < 3; c++) {
                mn[c] = fminf(mn[c], __shfl_xor(mn[c], o));
                mx[c] = fmaxf(mx[c], __shfl_xor(mx[c], o));
            }
        }
        int wv = t >> 6, ln = t & 63;
        if (ln == 0) {
#pragma unroll
            for (int c = 0; c < 3; c++) { sred[c][wv] = mn[c]; sred[3 + c][wv] = mx[c]; }
        }
        __syncthreads();
        if (t < 6) {
            bool ismin = t < 3;
            float v = sred[t][0];
            for (int w = 1; w < 8; w++) v = ismin ? fminf(v, sred[t][w]) : fmaxf(v, sred[t][w]);
            sbb[t] = v;
        }
        __syncthreads();
    }

    // --- Morton keys (6 bits/axis; resolution only affects pruning rate) ---
    {
        float bx = sbb[0], by = sbb[1], bz = sbb[2];
        float qsx = 63.0f / fmaxf(sbb[3] - bx, 1e-9f);
        float qsy = 63.0f / fmaxf(sbb[4] - by, 1e-9f);
        float qsz = 63.0f / fmaxf(sbb[5] - bz, 1e-9f);
        for (int p = t; p < NN; p += T) {
            unsigned qx = (unsigned)min(63, (int)((sxyz[p * 3 + 0] - bx) * qsx));
            unsigned qy = (unsigned)min(63, (int)((sxyz[p * 3 + 1] - by) * qsy));
            unsigned qz = (unsigned)min(63, (int)((sxyz[p * 3 + 2] - bz) * qsz));
            unsigned m = (expand3(qx) << 2) | (expand3(qy) << 1) | expand3(qz);  // 18 bits
            sortk[p] = (m << 13) | (unsigned)p;
        }
        __syncthreads();
        // bitonic sort of 8192 u32 keys (91 phases x 8 CE/thread)
        for (unsigned k = 2; k <= (unsigned)NN; k <<= 1) {
            for (unsigned j = k >> 1; j > 0; j >>= 1) {
#pragma unroll
                for (int r = 0; r < NN / 2 / T; r++) {  // 8
                    unsigned gid = (unsigned)(r * T + t);
                    unsigned i = ((gid & ~(j - 1)) << 1) | (gid & (j - 1));
                    unsigned p2 = i | j;
                    unsigned a = sortk[i], c2 = sortk[p2];
                    bool up = ((i & k) == 0);
                    if ((a > c2) == up) { sortk[i] = c2; sortk[p2] = a; }
                }
                __syncthreads();
            }
        }
    }

    // --- load 16 sorted points -> regs; exact half bboxes (2 x 8 pts) ---
    float px[P], py[P], pz[P], ds[P];
    int nidx[P];
    float l0x = 3.4e38f, l0y = 3.4e38f, l0z = 3.4e38f;
    float h0x = -3.4e38f, h0y = -3.4e38f, h0z = -3.4e38f;
    float l1x = 3.4e38f, l1y = 3.4e38f, l1z = 3.4e38f;
    float h1x = -3.4e38f, h1y = -3.4e38f, h1z = -3.4e38f;
#pragma unroll
    for (int j = 0; j < P; j++) {
        unsigned oi = sortk[t * P + j] & 8191u;
        float x = sxyz[oi * 3 + 0];
        float y = sxyz[oi * 3 + 1];
        float z = sxyz[oi * 3 + 2];
        px[j] = x; py[j] = y; pz[j] = z;
        ds[j] = 1e10f;
        nidx[j] = (int)~oi;
        if (j < 8) {
            l0x = fminf(l0x, x); h0x = fmaxf(h0x, x);
            l0y = fminf(l0y, y); h0y = fmaxf(h0y, y);
            l0z = fminf(l0z, z); h0z = fmaxf(h0z, z);
        } else {
            l1x = fminf(l1x, x); h1x = fmaxf(h1x, x);
            l1y = fminf(l1y, y); h1y = fmaxf(h1y, y);
            l1z = fminf(l1z, z); h1z = fmaxf(h1z, z);
        }
    }
    const float lox = fminf(l0x, l1x), loy = fminf(l0y, l1y), loz = fminf(l0z, l1z);
    const float hix = fmaxf(h0x, h1x), hiy = fmaxf(h0y, h1y), hiz = fmaxf(h0z, h1z);

    float cx = sxyz[0], cy = sxyz[1], cz = sxyz[2];   // same bits as xb[0..2]
    float* ob = new_xyz + (size_t)b * SS * 3;
    if (t == 0) {
        ob[0] = cx; ob[1] = cy; ob[2] = cz;
        // release: sample 0 (and this block's xyzf conversion) visible
        __hip_atomic_store(ctrl + b, 1, __ATOMIC_RELEASE, __HIP_MEMORY_SCOPE_AGENT);
    }
    const int wave = t >> 6, lane = t & 63;

    double hk0 = 0.0, hk1 = 0.0;     // per-half candidate keys (exact while skipping)
    float tb0 = 1e10f, tb1 = 1e10f;  // per-half max ds (hi word of hk*)

    for (int step = 1; step < SS; step++) {
        // conservative squared distance from centroid to outer bbox
        float ax = fmaxf(fmaxf(__fsub_rn(lox, cx), __fsub_rn(cx, hix)), 0.0f);
        float ay = fmaxf(fmaxf(__fsub_rn(loy, cy), __fsub_rn(cy, hiy)), 0.0f);
        float az = fmaxf(fmaxf(__fsub_rn(loz, cz), __fsub_rn(cz, hiz)), 0.0f);
        float lbdO = ax * ax + ay * ay + az * az;
        if (lbdO * 0.999f < fmaxf(tb0, tb1)) {
            // half 0
            float a0x = fmaxf(fmaxf(__fsub_rn(l0x, cx), __fsub_rn(cx, h0x)), 0.0f);
            float a0y = fmaxf(fmaxf(__fsub_rn(l0y, cy), __fsub_rn(cy, h0y)), 0.0f);
            float a0z = fmaxf(fmaxf(__fsub_rn(l0z, cz), __fsub_rn(cz, h0z)), 0.0f);
            float lbd0 = a0x * a0x + a0y * a0y + a0z * a0z;
            if (lbd0 * 0.999f < tb0) {
                double kk[8];
#pragma unroll
                for (int j = 0; j < 8; j++) {
                    float dx = __fsub_rn(px[j], cx);
                    float dy = __fsub_rn(py[j], cy);
                    float dz = __fsub_rn(pz[j], cz);
                    float d = __fadd_rn(__fadd_rn(__fmul_rn(dx, dx), __fmul_rn(dy, dy)),
                                        __fmul_rn(dz, dz));
                    float mm = fminf(ds[j], d);
                    ds[j] = mm;
                    kk[j] = __hiloint2double(__float_as_int(mm), nidx[j]);
                }
                double m0 = fmax(kk[0], kk[1]), m1 = fmax(kk[2], kk[3]);
                double m2 = fmax(kk[4], kk[5]), m3 = fmax(kk[6], kk[7]);
                hk0 = fmax(fmax(m0, m1), fmax(m2, m3));
                tb0 = __uint_as_float((unsigned)__double2hiint(hk0));
            }
            // half 1
            float a1x = fmaxf(fmaxf(__fsub_rn(l1x, cx), __fsub_rn(cx, h1x)), 0.0f);
            float a1y = fmaxf(fmaxf(__fsub_rn(l1y, cy), __fsub_rn(cy, h1y)), 0.0f);
            float a1z = fmaxf(fmaxf(__fsub_rn(l1z, cz), __fsub_rn(cz, h1z)), 0.0f);
            float lbd1 = a1x * a1x + a1y * a1y + a1z * a1z;
            if (lbd1 * 0.999f < tb1) {
                double kk[8];
#pragma unroll
                for (int j = 0; j < 8; j++) {
                    float dx = __fsub_rn(px[8 + j], cx);
                    float dy = __fsub_rn(py[8 + j], cy);
                    float dz = __fsub_rn(pz[8 + j], cz);
                    float d = __fadd_rn(__fadd_rn(__fmul_rn(dx, dx), __fmul_rn(dy, dy)),
                                        __fmul_rn(dz, dz));
                    float mm = fminf(ds[8 + j], d);
                    ds[8 + j] = mm;
                    kk[j] = __hiloint2double(__float_as_int(mm), nidx[8 + j]);
                }
                double m0 = fmax(kk[0], kk[1]), m1 = fmax(kk[2], kk[3]);
                double m2 = fmax(kk[4], kk[5]), m3 = fmax(kk[6], kk[7]);
                hk1 = fmax(fmax(m0, m1), fmax(m2, m3));
                tb1 = __uint_as_float((unsigned)__double2hiint(hk1));
            }
        }
        double bk = fmax(hk0, hk1);

        double wk = wave_max_dpp_f64(bk);
        const int par = step & 1;
        if (lane == 63) skey[par][wave] = wk;
        __syncthreads();

        double k0 = fmax(skey[par][0], skey[par][1]);
        double k1 = fmax(skey[par][2], skey[par][3]);
        double k2 = fmax(skey[par][4], skey[par][5]);
        double k3 = fmax(skey[par][6], skey[par][7]);
        double bkk = fmax(fmax(k0, k1), fmax(k2, k3));

        unsigned gidx = ~(unsigned)(unsigned long long)__double_as_longlong(bkk);
        cx = sxyz[gidx * 3 + 0];            // LDS broadcast (same bits as global)
        cy = sxyz[gidx * 3 + 1];
        cz = sxyz[gidx * 3 + 2];
        if (t == 0) {
            // streaming publish: sample store every step (+~26us total, r17),
            // release beacon every 64 steps (~16 total, negligible)
            ob[step * 3 + 0] = cx;
            ob[step * 3 + 1] = cy;
            ob[step * 3 + 2] = cz;
            if ((step & 63) == 0)
                __hip_atomic_store(ctrl + b, step + 1, __ATOMIC_RELEASE,
                                   __HIP_MEMORY_SCOPE_AGENT);
        }
    }

    if (t == 0)   // final release: all SS samples visible
        __hip_atomic_store(ctrl + b, SS, __ATOMIC_RELEASE, __HIP_MEMORY_SCOPE_AGENT);
}

// ---------------------------------------------------------------------------
// K3 (FUSED stats+lc): each block replays reduce_stats' EXACT reduction
// (same stride, butterfly order, association -> identical double bits),
// then does lc. (r24, validated.)
// ---------------------------------------------------------------------------
__global__ __launch_bounds__(256) void lc_kernel(const float* __restrict__ new_xyz,
                                                 const float* __restrict__ A,
                                                 const double* __restrict__ qstats,
                                                 float* __restrict__ lc,
                                                 double* __restrict__ bn1acc) {
    __shared__ double red[4];
    __shared__ double r1s[4], r2s[4];
    const int b = blockIdx.x / 6, c = blockIdx.x % 6;
    const int t = threadIdx.x;
    int wv = t >> 6, ln = t & 63;

    // --- replicated reduce_stats (bit-identical to the old kernel) ---
    double a = 0.0, bsum = 0.0;
    for (int i = t; i < BB * SS; i += 256) { a += qstats[2 * i]; bsum += qstats[2 * i + 1]; }
#pragma unroll
    for (int o = 32; o > 0; o >>= 1) { a += __shfl_xor(a, o); bsum += __shfl_xor(bsum, o); }
    if (ln == 0) { r1s[wv] = a; r2s[wv] = bsum; }
    __syncthreads();
    double sd = r1s[0] + r1s[1] + r1s[2] + r1s[3];
    double sq = r2s[0] + r2s[1] + r2s[2] + r2s[3];

    const double n = (double)BB * SS * KK * 3;
    double var = (sq - sd * sd / n) / (n - 1.0);
    float stdv = (float)sqrt(var);
    float denom = __fadd_rn(stdv, 1e-5f);

    double s1 = 0.0, s2 = 0.0;
    for (int r = 0; r < 4; r++) {
        int s = r * 256 + t;
        float v;
        if (c < 3) {
            v = A[((size_t)b * SS + s) * 3 + c] / denom;
        } else {
            float ww = new_xyz[((size_t)b * SS + s) * 3 + (c - 3)];
            v = __fadd_rn(ww, ww);
        }
        lc[((size_t)b * 6 + c) * SS + s] = v;
        s1 += (double)v;
        s2 += (double)v * (double)v;
    }
#pragma unroll
    for (int off = 32; off > 0; off >>= 1) { s1 += __shfl_down(s1, off); s2 += __shfl_down(s2, off); }
    if (ln == 0) red[wv] = s1;
    __syncthreads();
    if (t == 0) atomicAdd(&bn1acc[c * 2 + 0], red[0] + red[1] + red[2] + red[3]);
    __syncthreads();
    if (ln == 0) red[wv] = s2;
    __syncthreads();
    if (t == 0) atomicAdd(&bn1acc[c * 2 + 1], red[0] + red[1] + red[2] + red[3]);
}

// ---------------------------------------------------------------------------
// K4 (FUSED cdist+bn2): per-batch BN1+cdist; LAST block (device ticket) runs
// bn2. (r24, validated on HW.)
// ---------------------------------------------------------------------------
__global__ __launch_bounds__(256) void cdist_kernel(const float* __restrict__ lc,
                                                    const double* __restrict__ bn1acc,
                                                    const float* __restrict__ params,
                                                    float* __restrict__ tf,
                                                    void* __restrict__ out_raw,
                                                    int* __restrict__ cnt) {
    __shared__ float sy[6 * SS];
    __shared__ int lastf;
    const int b = blockIdx.x, t = threadIdx.x;
    float mean[6], sde[6], gg[6], bt[6];
    const double n = (double)BB * SS;
#pragma unroll
    for (int c = 0; c < 6; c++) {
        double m = bn1acc[c * 2 + 0] / n;
        double v = bn1acc[c * 2 + 1] / n - m * m;
        mean[c] = (float)m;
        sde[c] = sqrtf((float)v + 1e-5f);
        gg[c] = params[c];
        bt[c] = params[6 + c];
    }
    for (int r = 0; r < 24; r++) {
        int g = r * 256 + t;
        int c = g >> 10;
        float v = lc[(size_t)b * 6 * SS + g];
        float y = (v - mean[c]) / sde[c] * gg[c] + bt[c];
        sy[g] = fmaxf(y, 0.0f);
    }
    __syncthreads();
    if (t < 6) tf[b * 36 + t * 7] = 0.0f;

    const int w = t >> 6, lane = t & 63;
    const int PI[15] = {0,0,0,0,0,1,1,1,1,2,2,2,3,3,4};
    const int PJ[15] = {1,2,3,4,5,2,3,4,5,3,4,5,4,5,5};
    for (int r = 0; r < 4; r++) {
        int p = w + r * 4;
        if (p < 15) {
            int i = PI[p], j = PJ[p];
            float acc = 0.0f;
            for (int m2 = 0; m2 < 16; m2++) {
                int s = lane + m2 * 64;
                float d = sy[i * SS + s] - sy[j * SS + s];
                acc += d * d;
            }
#pragma unroll
            for (int off = 32; off > 0; off >>= 1) acc += __shfl_down(acc, off);
            if (lane == 0) {
                float v = acc > 0.0f ? sqrtf(acc) : 0.0f;
                const float FACTOR = 1.0f;
                tf[b * 36 + i * 6 + j] = (j == i + 1) ? v * FACTOR : v;
                tf[b * 36 + j * 6 + i] = v;
            }
        }
    }

    // ---- last-block bn2 (ticket pattern) ----
    __syncthreads();      // all tf stores issued block-wide
    __threadfence();      // each thread: device-visible flush of its stores
    __syncthreads();      // all fences complete
    if (t == 0) { lastf = (atomicAdd(cnt, 1) == BB - 1) ? 1 : 0; }
    __syncthreads();
    if (lastf) {
        __threadfence();  // acquire: other blocks' tf now visible
        if (t < 36) {
            int f = t;
            bool isbf = params[84] != 0.0f;
            float x[16]; float sum = 0.0f;
#pragma unroll
            for (int bb2 = 0; bb2 < 16; bb2++) { x[bb2] = tf[bb2 * 36 + f]; sum += x[bb2]; }
            float mean2 = sum * 0.0625f;
            float vs = 0.0f;
#pragma unroll
            for (int bb2 = 0; bb2 < 16; bb2++) { float d = x[bb2] - mean2; vs += d * d; }
            float var2 = vs * 0.0625f;
            float denom2 = sqrtf(var2 + 1e-5f);
            float g = params[12 + f], bb = params[48 + f];
#pragma unroll
            for (int bb2 = 0; bb2 < 16; bb2++) {
                float y = (x[bb2] - mean2) / denom2 * g + bb;
                y = fmaxf(y, 0.0f);
                if (isbf) ((__hip_bfloat16*)out_raw)[bb2 * 36 + f] = __float2bfloat16(y);
                else      ((float*)out_raw)[bb2 * 36 + f] = y;
            }
        }
    }
}

// ---------------------------------------------------------------------------
// Workspace layout (bytes):
//   0        : xyzf     float[16*8192*3]   (1572864)
//   1572864  : new_xyz  float[16*1024*3]   (196608)
//   1769472  : A        float[16*1024*3]   (196608)
//   1966080  : lc       float[16*6*1024]   (393216)  [first 68B = ctrl during
//              fps_kernel: ctrl[0..15]=progress, ctrl[16]=qdone; lc_kernel
//              overwrites afterwards]
//   2359296  : tfcw     float[16*36]       (2304)
//   2361600  : stats    double[14]         (bn1acc = stats+2)
//   2361712  : params   float[85]          (ends 2362052)
//   2362056  : done[0]=spare, done[1]=cdist ticket (zeroed per launch)
//   2362112  : qstats   double[16384*2]    (262144)
// ---------------------------------------------------------------------------
extern "C" void kernel_launch(void* const* d_in, const int* in_sizes, int n_in,
                              void* d_out, int out_size, void* d_ws, size_t ws_size,
                              hipStream_t stream) {
    const void* xyz_raw = d_in[0];
    const void* g1r = d_in[1]; const void* b1r = d_in[2];
    const void* g2r = d_in[3]; const void* b2r = d_in[4];
    {
        const void* six[2] = {nullptr, nullptr}; int n6 = 0;
        const void* t36[2] = {nullptr, nullptr}; int n36 = 0;
        const void* big = nullptr;
        for (int i = 0; i < n_in; i++) {
            if (in_sizes[i] == BB * NN * 3) big = d_in[i];
            else if (in_sizes[i] == 6  && n6  < 2) six[n6++]  = d_in[i];
            else if (in_sizes[i] == 36 && n36 < 2) t36[n36++] = d_in[i];
        }
        if (big && n6 == 2 && n36 == 2) {
            xyz_raw = big; g1r = six[0]; b1r = six[1]; g2r = t36[0]; b2r = t36[1];
        }
    }

    char* ws = (char*)d_ws;
    float* xyzf    = (float*)(ws + 0);
    float* new_xyz = (float*)(ws + 1572864);
    float* A       = (float*)(ws + 1769472);
    float* lc      = (float*)(ws + 1966080);
    int* ctrl      = (int*)(ws + 1966080);   // aliases lc head during fps_kernel
    float* tf      = (float*)(ws + 2359296);
    double* stats  = (double*)(ws + 2361600);
    double* bn1acc = stats + 2;
    float* params  = (float*)(ws + 2361712);
    int* done      = (int*)(ws + 2362056);
    double* qstats = (double*)(ws + 2362112);

    hipMemsetAsync(stats, 0, 14 * sizeof(double), stream);
    hipMemsetAsync(done, 0, 2 * sizeof(int), stream);
    hipMemsetAsync(ctrl, 0, 17 * sizeof(int), stream);
    hipLaunchKernelGGL(fps_kernel, dim3(256), dim3(512), 0, stream,
                       xyz_raw, g1r, b1r, g2r, b2r, xyzf, new_xyz, params, d_out,
                       ctrl, A, qstats);
    hipLaunchKernelGGL(lc_kernel,    dim3(96),   dim3(256), 0, stream, new_xyz, A, qstats, lc, bn1acc);
    hipLaunchKernelGGL(cdist_kernel, dim3(16),   dim3(256), 0, stream, lc, bn1acc, params, tf,
                       d_out, done + 1);

    (void)in_sizes; (void)n_in; (void)out_size; (void)ws_size;
}

// Round 12
// 1103.111 us; speedup vs baseline: 1.3195x; 1.3195x over previous
//
#include <hip/hip_runtime.h>
#include <hip/hip_bf16.h>

// Problem constants (from reference)
constexpr int BB = 16;     // batches
constexpr int NN = 8192;   // points
constexpr int SS = 1024;   // samples (FPS)
constexpr int KK = 32;     // kNN
constexpr int BUFC = 256;  // per-wave candidate buffer (keys <= That)

__device__ __forceinline__ float b2f(__hip_bfloat16 h) { return __bfloat162float(h); }

// Monotone map f32 -> u32 (order-preserving, bijective; d is never -0 here).
__device__ __forceinline__ unsigned mkey32(float d) {
    unsigned u = __float_as_uint(d);
    return u ^ (0x80000000u | (unsigned)((int)u >> 31));
}

// Deterministic distance key for point idx vs query (qx,qy,qz,qq).
// Same expression sequence every call -> bit-identical results (IEEE, no FMA).
__device__ __forceinline__ unsigned long long dist_key(const float* __restrict__ pb,
                                                       int idx, float qx, float qy,
                                                       float qz, float qq) {
    float px = pb[idx * 3 + 0];
    float py = pb[idx * 3 + 1];
    float pz = pb[idx * 3 + 2];
    float dot = __fadd_rn(__fadd_rn(__fmul_rn(qx, px), __fmul_rn(qy, py)), __fmul_rn(qz, pz));
    float pp  = __fadd_rn(__fadd_rn(__fmul_rn(px, px), __fmul_rn(py, py)), __fmul_rn(pz, pz));
    float d = __fadd_rn(__fadd_rn(__fmul_rn(-2.0f, dot), qq), pp);
    return ((unsigned long long)mkey32(d) << 32) | (unsigned)idx;
}

// DPP lane-move of a u64 (both halves move identically).
template <int CTRL, int RMASK>
__device__ __forceinline__ unsigned long long dppmove_u64(unsigned long long v) {
    int lo = (int)(unsigned)v, hi = (int)(unsigned)(v >> 32);
    int nlo = __builtin_amdgcn_update_dpp(lo, lo, CTRL, RMASK, 0xf, false);
    int nhi = __builtin_amdgcn_update_dpp(hi, hi, CTRL, RMASK, 0xf, false);
    return ((unsigned long long)(unsigned)nhi << 32) | (unsigned)nlo;
}

// FPS keys are (dist_bits<<32)|~idx with dist_bits <= 0x501502F9 -> as f64 they
// are positive, finite, non-NaN, and bit order == numeric order. v_max_f64
// (1 instr) replaces cmp+2*cndmask in every reduce stage.
template <int CTRL, int RMASK>
__device__ __forceinline__ double dppmax_f64(double v) {
    double m = __longlong_as_double(
        dppmove_u64<CTRL, RMASK>((unsigned long long)__double_as_longlong(v)));
    return fmax(v, m);
}

// Wave64 max-reduce via DPP. Lane 63 holds the max.
__device__ __forceinline__ double wave_max_dpp_f64(double v) {
    v = dppmax_f64<0x121, 0xf>(v);  // row_ror:1
    v = dppmax_f64<0x122, 0xf>(v);  // row_ror:2
    v = dppmax_f64<0x124, 0xf>(v);  // row_ror:4
    v = dppmax_f64<0x128, 0xf>(v);  // row_ror:8
    v = dppmax_f64<0x142, 0xa>(v);  // row_bcast:15 -> rows 1,3
    v = dppmax_f64<0x143, 0xc>(v);  // row_bcast:31 -> rows 2,3
    return v;
}

// Cross-lane bitonic sort of 64 u64 keys (ascending); lane i ends with i-th smallest.
__device__ __forceinline__ unsigned long long bitonic64(unsigned long long v, int lane) {
#pragma unroll
    for (int k = 2; k <= 64; k <<= 1) {
#pragma unroll
        for (int j = k >> 1; j > 0; j >>= 1) {
            unsigned long long p = __shfl_xor(v, j);
            bool up = ((lane & k) == 0);
            bool lower = ((lane & j) == 0);
            bool take_min = (up == lower);
            v = take_min ? (p < v ? p : v) : (p > v ? p : v);
        }
    }
    return v;
}

// 10-bit -> every-3rd-bit expansion (Morton interleave helper).
__device__ __forceinline__ unsigned expand3(unsigned v) {
    v &= 0x3FFu;
    v = (v | (v << 16)) & 0x030000FFu;
    v = (v | (v << 8))  & 0x0300F00Fu;
    v = (v | (v << 4))  & 0x030C30C3u;
    v = (v | (v << 2))  & 0x09249249u;
    return v;
}

// ---------------------------------------------------------------------------
// K1: FUSED convert + FPS + DVFS heaters (r24 configuration — best measured
// 1105.1us; restored verbatim after r25's streaming-knn experiment regressed
// to 1455: concurrent knn traffic (FETCH 878KB->5MB) inflated the
// latency-bound fps chain by +445us — r14's interference lesson at chip
// scope. Concurrent-overlap axis is closed.)
//
// Heater intensity curve (fps_cost, tail_benefit): r18 none 920+235=1155;
// r22 35%FMA 938+202=1140; r21 fullFMA 963+153=1116 (OPT); r23 fullINT
// 997+129=1127. Optimum = full-FMA always-on.
//
// Fusions (all bit-identical, r24-validated): convert folded into fps
// blocks (own batch) + heater block 16 (params/sentinel); reduce_stats
// replicated into lc blocks; bn2 via last-block ticket in cdist.
//
// fps math = r18 chain: Morton sort, 16 pts/thread, outer+half bbox prune,
// rn-sequence refresh, f64 DPP reduce, LDS samples buffer, one cooperative
// global write at the end.
//
// Carried lessons: waves_per_eu(2,2) pins 256-reg budget (r5/r6); multi-CU
// FPS loses (r8/r9); knn fusion/overlap loses (r14/r25); per-step global
// store costs ~26us (r17); issue-work cuts don't move fps (r15/r18);
// 2-batch state spills and can't cut wall time (r19/r20).
// ---------------------------------------------------------------------------
__global__ __attribute__((amdgpu_flat_work_group_size(512, 512)))
__attribute__((amdgpu_waves_per_eu(2, 2)))
void fps_kernel(const void* __restrict__ xyz_raw, const void* __restrict__ g1r,
                const void* __restrict__ b1r, const void* __restrict__ g2r,
                const void* __restrict__ b2r, float* __restrict__ xyzf,
                float* __restrict__ new_xyz, float* __restrict__ params,
                void* __restrict__ out_raw, int* __restrict__ done) {
    __shared__ float sxyz[NN * 3];      // 96 KB coord table (ORIGINAL order)
    __shared__ unsigned sortk[NN];      // 32 KB sort keys; reused as samples[]
    __shared__ double skey[2][8];
    __shared__ float sred[6][8];
    __shared__ float sbb[6];

    // dtype detection (all blocks; same data -> same result)
    const unsigned short* u = (const unsigned short*)xyz_raw;
    unsigned short sdet = u[2 * (threadIdx.x & 63)];
    int e = (sdet >> 7) & 0xFF;
    unsigned long long mball = __ballot(e >= 100 && e <= 140);
    const bool isbf = __popcll(mball) > 48;

    if (blockIdx.x >= 16) {
        // block 16: params conversion + d_out sentinel (was convert_kernel)
        if (blockIdx.x == 16) {
            int t = threadIdx.x;
            if (t < 85) {
                if (t == 84) {
                    params[84] = isbf ? 1.0f : 0.0f;
                } else {
                    const void* src; int off;
                    if (t < 6)       { src = g1r; off = t; }
                    else if (t < 12) { src = b1r; off = t - 6; }
                    else if (t < 48) { src = g2r; off = t - 12; }
                    else             { src = b2r; off = t - 48; }
                    params[t] = isbf ? b2f(((const __hip_bfloat16*)src)[off])
                                     : ((const float*)src)[off];
                }
            }
            if (t >= 128 && t < 192) {
                for (int i = t - 128; i < 576; i += 64) {
                    if (isbf) ((__hip_bfloat16*)out_raw)[i] = __float2bfloat16(1.0f);
                    else      ((float*)out_raw)[i] = 1.0f;
                }
            }
        }
        // -------- DVFS heater (r21 verbatim): FMA spin until fps done.
        float a0 = 1.0f + threadIdx.x * 1e-7f, a1 = 1.1f, a2 = 1.2f, a3 = 1.3f;
        const float mql = 1.0000001f, cdl = 1e-9f;
        for (int it = 0; it < 20000; ++it) {
#pragma unroll
            for (int k = 0; k < 16; ++k) {
                a0 = __fmaf_rn(a0, mql, cdl);
                a1 = __fmaf_rn(a1, mql, cdl);
                a2 = __fmaf_rn(a2, mql, cdl);
                a3 = __fmaf_rn(a3, mql, cdl);
            }
            if ((it & 7) == 0) {
                int d = __hip_atomic_load(done, __ATOMIC_RELAXED,
                                          __HIP_MEMORY_SCOPE_AGENT);
                if (d >= 16) break;
            }
        }
        asm volatile("" :: "v"(a0), "v"(a1), "v"(a2), "v"(a3));
        return;
    }

    constexpr int T = 512, P = NN / T;  // 16 contiguous sorted points per thread
    const int b = blockIdx.x, t = threadIdx.x;

    // --- inline convert: raw -> f32 -> xyzf (for knn) + sxyz (LDS stage) ---
    {
        float* xout = xyzf + (size_t)b * NN * 3;
        if (isbf) {
            const __hip_bfloat16* p = (const __hip_bfloat16*)xyz_raw + (size_t)b * NN * 3;
            for (int i = t; i < NN * 3; i += T) {
                float v = b2f(p[i]);    // exact widening, same bits as before
                xout[i] = v;
                sxyz[i] = v;
            }
        } else {
            const float* p = (const float*)xyz_raw + (size_t)b * NN * 3;
            for (int i = t; i < NN * 3; i += T) {
                float v = p[i];
                xout[i] = v;
                sxyz[i] = v;
            }
        }
    }
    __syncthreads();

    // --- batch bbox (min/max per axis) for Morton quantization ---
    {
        float mn[3] = {3.4e38f, 3.4e38f, 3.4e38f};
        float mx[3] = {-3.4e38f, -3.4e38f, -3.4e38f};
        for (int j = 0; j < P; j++) {
            int p = t + j * T;
#pragma unroll
            for (int c = 0; c < 3; c++) {
                float v = sxyz[p * 3 + c];
                mn[c] = fminf(mn[c], v);
                mx[c] = fmaxf(mx[c], v);
            }
        }
#pragma unroll
        for (int o = 32; o > 0; o >>= 1) {
#pragma unroll
            for (int c = 0; c < 3; c++) {
                mn[c] = fminf(mn[c], __shfl_xor(mn[c], o));
                mx[c] = fmaxf(mx[c], __shfl_xor(mx[c], o));
            }
        }
        int wv = t >> 6, ln = t & 63;
        if (ln == 0) {
#pragma unroll
            for (int c = 0; c < 3; c++) { sred[c][wv] = mn[c]; sred[3 + c][wv] = mx[c]; }
        }
        __syncthreads();
        if (t < 6) {
            bool ismin = t < 3;
            float v = sred[t][0];
            for (int w = 1; w < 8; w++) v = ismin ? fminf(v, sred[t][w]) : fmaxf(v, sred[t][w]);
            sbb[t] = v;
        }
        __syncthreads();
    }

    // --- Morton keys (6 bits/axis; resolution only affects pruning rate) ---
    {
        float bx = sbb[0], by = sbb[1], bz = sbb[2];
        float qsx = 63.0f / fmaxf(sbb[3] - bx, 1e-9f);
        float qsy = 63.0f / fmaxf(sbb[4] - by, 1e-9f);
        float qsz = 63.0f / fmaxf(sbb[5] - bz, 1e-9f);
        for (int p = t; p < NN; p += T) {
            unsigned qx = (unsigned)min(63, (int)((sxyz[p * 3 + 0] - bx) * qsx));
            unsigned qy = (unsigned)min(63, (int)((sxyz[p * 3 + 1] - by) * qsy));
            unsigned qz = (unsigned)min(63, (int)((sxyz[p * 3 + 2] - bz) * qsz));
            unsigned m = (expand3(qx) << 2) | (expand3(qy) << 1) | expand3(qz);  // 18 bits
            sortk[p] = (m << 13) | (unsigned)p;
        }
        __syncthreads();
        // bitonic sort of 8192 u32 keys (91 phases x 8 CE/thread)
        for (unsigned k = 2; k <= (unsigned)NN; k <<= 1) {
            for (unsigned j = k >> 1; j > 0; j >>= 1) {
#pragma unroll
                for (int r = 0; r < NN / 2 / T; r++) {  // 8
                    unsigned gid = (unsigned)(r * T + t);
                    unsigned i = ((gid & ~(j - 1)) << 1) | (gid & (j - 1));
                    unsigned p2 = i | j;
                    unsigned a = sortk[i], c2 = sortk[p2];
                    bool up = ((i & k) == 0);
                    if ((a > c2) == up) { sortk[i] = c2; sortk[p2] = a; }
                }
                __syncthreads();
            }
        }
    }

    // --- load 16 sorted points -> regs; exact half bboxes (2 x 8 pts) ---
    float px[P], py[P], pz[P], ds[P];
    int nidx[P];
    float l0x = 3.4e38f, l0y = 3.4e38f, l0z = 3.4e38f;
    float h0x = -3.4e38f, h0y = -3.4e38f, h0z = -3.4e38f;
    float l1x = 3.4e38f, l1y = 3.4e38f, l1z = 3.4e38f;
    float h1x = -3.4e38f, h1y = -3.4e38f, h1z = -3.4e38f;
#pragma unroll
    for (int j = 0; j < P; j++) {
        unsigned oi = sortk[t * P + j] & 8191u;
        float x = sxyz[oi * 3 + 0];
        float y = sxyz[oi * 3 + 1];
        float z = sxyz[oi * 3 + 2];
        px[j] = x; py[j] = y; pz[j] = z;
        ds[j] = 1e10f;
        nidx[j] = (int)~oi;
        if (j < 8) {
            l0x = fminf(l0x, x); h0x = fmaxf(h0x, x);
            l0y = fminf(l0y, y); h0y = fmaxf(h0y, y);
            l0z = fminf(l0z, z); h0z = fmaxf(h0z, z);
        } else {
            l1x = fminf(l1x, x); h1x = fmaxf(h1x, x);
            l1y = fminf(l1y, y); h1y = fmaxf(h1y, y);
            l1z = fminf(l1z, z); h1z = fmaxf(h1z, z);
        }
    }
    const float lox = fminf(l0x, l1x), loy = fminf(l0y, l1y), loz = fminf(l0z, l1z);
    const float hix = fmaxf(h0x, h1x), hiy = fmaxf(h0y, h1y), hiz = fmaxf(h0z, h1z);

    __syncthreads();   // all sortk reads done -> safe to reuse as samples[]
    float* samples = (float*)sortk;   // 12 KB of the 32 KB, setup-dead space

    float cx = sxyz[0], cy = sxyz[1], cz = sxyz[2];   // same bits as xb[0..2]
    if (t == 0) { samples[0] = cx; samples[1] = cy; samples[2] = cz; }
    const int wave = t >> 6, lane = t & 63;

    double hk0 = 0.0, hk1 = 0.0;     // per-half candidate keys (exact while skipping)
    float tb0 = 1e10f, tb1 = 1e10f;  // per-half max ds (hi word of hk*)

    for (int step = 1; step < SS; step++) {
        // conservative squared distance from centroid to outer bbox
        float ax = fmaxf(fmaxf(__fsub_rn(lox, cx), __fsub_rn(cx, hix)), 0.0f);
        float ay = fmaxf(fmaxf(__fsub_rn(loy, cy), __fsub_rn(cy, hiy)), 0.0f);
        float az = fmaxf(fmaxf(__fsub_rn(loz, cz), __fsub_rn(cz, hiz)), 0.0f);
        float lbdO = ax * ax + ay * ay + az * az;
        if (lbdO * 0.999f < fmaxf(tb0, tb1)) {
            // half 0
            float a0x = fmaxf(fmaxf(__fsub_rn(l0x, cx), __fsub_rn(cx, h0x)), 0.0f);
            float a0y = fmaxf(fmaxf(__fsub_rn(l0y, cy), __fsub_rn(cy, h0y)), 0.0f);
            float a0z = fmaxf(fmaxf(__fsub_rn(l0z, cz), __fsub_rn(cz, h0z)), 0.0f);
            float lbd0 = a0x * a0x + a0y * a0y + a0z * a0z;
            if (lbd0 * 0.999f < tb0) {
                double kk[8];
#pragma unroll
                for (int j = 0; j < 8; j++) {
                    float dx = __fsub_rn(px[j], cx);
                    float dy = __fsub_rn(py[j], cy);
                    float dz = __fsub_rn(pz[j], cz);
                    float d = __fadd_rn(__fadd_rn(__fmul_rn(dx, dx), __fmul_rn(dy, dy)),
                                        __fmul_rn(dz, dz));
                    float mm = fminf(ds[j], d);
                    ds[j] = mm;
                    kk[j] = __hiloint2double(__float_as_int(mm), nidx[j]);
                }
                double m0 = fmax(kk[0], kk[1]), m1 = fmax(kk[2], kk[3]);
                double m2 = fmax(kk[4], kk[5]), m3 = fmax(kk[6], kk[7]);
                hk0 = fmax(fmax(m0, m1), fmax(m2, m3));
                tb0 = __uint_as_float((unsigned)__double2hiint(hk0));
            }
            // half 1
            float a1x = fmaxf(fmaxf(__fsub_rn(l1x, cx), __fsub_rn(cx, h1x)), 0.0f);
            float a1y = fmaxf(fmaxf(__fsub_rn(l1y, cy), __fsub_rn(cy, h1y)), 0.0f);
            float a1z = fmaxf(fmaxf(__fsub_rn(l1z, cz), __fsub_rn(cz, h1z)), 0.0f);
            float lbd1 = a1x * a1x + a1y * a1y + a1z * a1z;
            if (lbd1 * 0.999f < tb1) {
                double kk[8];
#pragma unroll
                for (int j = 0; j < 8; j++) {
                    float dx = __fsub_rn(px[8 + j], cx);
                    float dy = __fsub_rn(py[8 + j], cy);
                    float dz = __fsub_rn(pz[8 + j], cz);
                    float d = __fadd_rn(__fadd_rn(__fmul_rn(dx, dx), __fmul_rn(dy, dy)),
                                        __fmul_rn(dz, dz));
                    float mm = fminf(ds[8 + j], d);
                    ds[8 + j] = mm;
                    kk[j] = __hiloint2double(__float_as_int(mm), nidx[8 + j]);
                }
                double m0 = fmax(kk[0], kk[1]), m1 = fmax(kk[2], kk[3]);
                double m2 = fmax(kk[4], kk[5]), m3 = fmax(kk[6], kk[7]);
                hk1 = fmax(fmax(m0, m1), fmax(m2, m3));
                tb1 = __uint_as_float((unsigned)__double2hiint(hk1));
            }
        }
        double bk = fmax(hk0, hk1);

        double wk = wave_max_dpp_f64(bk);
        const int par = step & 1;
        if (lane == 63) skey[par][wave] = wk;
        __syncthreads();

        double k0 = fmax(skey[par][0], skey[par][1]);
        double k1 = fmax(skey[par][2], skey[par][3]);
        double k2 = fmax(skey[par][4], skey[par][5]);
        double k3 = fmax(skey[par][6], skey[par][7]);
        double bkk = fmax(fmax(k0, k1), fmax(k2, k3));

        unsigned gidx = ~(unsigned)(unsigned long long)__double_as_longlong(bkk);
        cx = sxyz[gidx * 3 + 0];            // LDS broadcast (same bits as global)
        cy = sxyz[gidx * 3 + 1];
        cz = sxyz[gidx * 3 + 2];
        if (t == 0) {                        // LDS only: no vmcnt drain at barrier
            samples[step * 3 + 0] = cx;
            samples[step * 3 + 1] = cy;
            samples[step * 3 + 2] = cz;
        }
    }

    __syncthreads();
    // cooperative coalesced write of all 1024 samples
    float* o = new_xyz + (size_t)b * SS * 3;
    for (int i = t; i < SS * 3; i += T) o[i] = samples[i];

    if (t == 0) atomicAdd(done, 1);   // release the heaters
}

// ---------------------------------------------------------------------------
// K2 (RECOMPUTE): kNN via exact threshold selection, one wave per query,
// NO per-lane key array.
// r13/r14 LESSON: mk[128] spilled to scratch -> 2.2 GB HBM traffic; the
// RECOMPUTE form (pass 1 lane-min only; pass 2 recomputes keys) keeps
// everything in registers; IEEE ops on immutable inputs -> bit-identical.
// ---------------------------------------------------------------------------
__global__ __launch_bounds__(256, 2) void knn_kernel(const float* __restrict__ xyzf,
                                                     const float* __restrict__ new_xyz,
                                                     float* __restrict__ A,
                                                     double* __restrict__ qstats) {
    __shared__ unsigned long long buf[4][BUFC];
    const int t = threadIdx.x;
    const int lane = t & 63, wv = t >> 6;
    const int w = blockIdx.x * 4 + wv;          // global wave id = query id
    const int b = w >> 10, s = w & 1023;

    const float* q = new_xyz + ((size_t)b * SS + s) * 3;
    float qx = q[0], qy = q[1], qz = q[2];
    float qq = __fadd_rn(__fadd_rn(__fmul_rn(qx, qx), __fmul_rn(qy, qy)), __fmul_rn(qz, qz));

    const float* pb = xyzf + (size_t)b * NN * 3;
    const unsigned long long ltmask = (1ull << lane) - 1ull;

    // pass 1: lane-min key only (no storage)
    unsigned long long lmin = ~0ull;
    for (int j = 0; j < 128; j++) {
        unsigned long long key = dist_key(pb, j * 64 + lane, qx, qy, qz, qq);
        lmin = key < lmin ? key : lmin;
    }

    unsigned long long vs = bitonic64(lmin, lane);
    unsigned long long That = __shfl(vs, 31);

    // pass 2: recompute keys, compact keys <= That into LDS
    for (int i = lane; i < BUFC; i += 64) buf[wv][i] = ~0ull;
    int base = 0;
    for (int j = 0; j < 128; j++) {
        unsigned long long key = dist_key(pb, j * 64 + lane, qx, qy, qz, qq);
        bool f = key <= That;
        unsigned long long bal = __ballot(f);
        int pos = base + __popcll(bal & ltmask);
        if (f && pos < BUFC) buf[wv][pos] = key;
        base += __popcll(bal);
    }

    // rare recovery: tighten threshold (recompute inside search)
    if (base > BUFC) {
        unsigned lo = 0, hi = (unsigned)(That >> 32);
        for (int it = 0; it < 32; it++) {
            unsigned mid = lo + ((hi - lo) >> 1);
            int c = 0;
            for (int j = 0; j < 128; j++) {
                unsigned long long key = dist_key(pb, j * 64 + lane, qx, qy, qz, qq);
                c += ((unsigned)(key >> 32) <= mid) ? 1 : 0;
            }
#pragma unroll
            for (int o = 32; o > 0; o >>= 1) c += __shfl_xor(c, o);
            if (c >= 32) hi = mid; else lo = mid + 1;
        }
        That = ((unsigned long long)hi << 32) | 0xFFFFFFFFull;
        for (int i = lane; i < BUFC; i += 64) buf[wv][i] = ~0ull;
        base = 0;
        for (int j = 0; j < 128; j++) {
            unsigned long long key = dist_key(pb, j * 64 + lane, qx, qy, qz, qq);
            bool f = key <= That;
            unsigned long long bal = __ballot(f);
            int pos = base + __popcll(bal & ltmask);
            if (f && pos < BUFC) buf[wv][pos] = key;
            base += __popcll(bal);
        }
        if (base > BUFC) base = BUFC;
    }

    int M = base;
    unsigned long long kept = ~0ull;
    if (M <= 64) {
        unsigned long long v = (lane < M) ? buf[wv][lane] : ~0ull;
        v = bitonic64(v, lane);
        kept = v;
    } else {
        unsigned long long c0 = buf[wv][lane];
        unsigned long long c1 = buf[wv][64 + lane];
        unsigned long long c2 = buf[wv][128 + lane];
        unsigned long long c3 = buf[wv][192 + lane];
        for (int r = 0; r < KK; r++) {
            unsigned long long m01 = c0 < c1 ? c0 : c1;
            unsigned long long m23 = c2 < c3 ? c2 : c3;
            unsigned long long mm = m01 < m23 ? m01 : m23;
#pragma unroll
            for (int o = 32; o > 0; o >>= 1) {
                unsigned long long t2 = __shfl_xor(mm, o);
                mm = t2 < mm ? t2 : mm;
            }
            if (lane == r) kept = mm;
            c0 = (c0 == mm) ? ~0ull : c0;
            c1 = (c1 == mm) ? ~0ull : c1;
            c2 = (c2 == mm) ? ~0ull : c2;
            c3 = (c3 == mm) ? ~0ull : c3;
        }
    }

    bool act = (lane < KK);
    float gx = 0.0f, gy = 0.0f, gz = 0.0f;
    if (act) {
        unsigned nidx = (unsigned)kept;
        gx = pb[nidx * 3 + 0];
        gy = pb[nidx * 3 + 1];
        gz = pb[nidx * 3 + 2];
    }
    float dx = __fsub_rn(gx, qx);
    float dy = __fsub_rn(gy, qy);
    float dz = __fsub_rn(gz, qz);
    float mx = act ? dx : -3.402823466e38f;
    float my = act ? dy : -3.402823466e38f;
    float mz = act ? dz : -3.402823466e38f;
    float sx = act ? dx : 0.0f;
    float sy = act ? dy : 0.0f;
    float sz = act ? dz : 0.0f;
    double s1 = act ? ((double)dx + (double)dy + (double)dz) : 0.0;
    double s2 = act ? ((double)dx * dx + (double)dy * dy + (double)dz * dz) : 0.0;
#pragma unroll
    for (int o = 32; o > 0; o >>= 1) {
        mx = fmaxf(mx, __shfl_xor(mx, o));
        my = fmaxf(my, __shfl_xor(my, o));
        mz = fmaxf(mz, __shfl_xor(mz, o));
        sx += __shfl_xor(sx, o);
        sy += __shfl_xor(sy, o);
        sz += __shfl_xor(sz, o);
        s1 += __shfl_xor(s1, o);
        s2 += __shfl_xor(s2, o);
    }
    if (lane == 0) {
        float* a = A + ((size_t)b * SS + s) * 3;
        a[0] = __fadd_rn(mx, __fmul_rn(sx, 0.03125f));
        a[1] = __fadd_rn(my, __fmul_rn(sy, 0.03125f));
        a[2] = __fadd_rn(mz, __fmul_rn(sz, 0.03125f));
        qstats[2 * w + 0] = s1;
        qstats[2 * w + 1] = s2;
    }
}

// ---------------------------------------------------------------------------
// K3 (FUSED stats+lc): each block replays reduce_stats' EXACT reduction
// (same stride, same shfl_xor butterfly order, same r1[0]+r1[1]+r1[2]+r1[3]
// association -> identical double bits), then does lc. Deletes one launch;
// redundant 256KB L2 read per block ~ 0.7us total.
// ---------------------------------------------------------------------------
__global__ __launch_bounds__(256) void lc_kernel(const float* __restrict__ new_xyz,
                                                 const float* __restrict__ A,
                                                 const double* __restrict__ qstats,
                                                 float* __restrict__ lc,
                                                 double* __restrict__ bn1acc) {
    __shared__ double red[4];
    __shared__ double r1s[4], r2s[4];
    const int b = blockIdx.x / 6, c = blockIdx.x % 6;
    const int t = threadIdx.x;
    int wv = t >> 6, ln = t & 63;

    // --- replicated reduce_stats (bit-identical to the old kernel) ---
    double a = 0.0, bsum = 0.0;
    for (int i = t; i < BB * SS; i += 256) { a += qstats[2 * i]; bsum += qstats[2 * i + 1]; }
#pragma unroll
    for (int o = 32; o > 0; o >>= 1) { a += __shfl_xor(a, o); bsum += __shfl_xor(bsum, o); }
    if (ln == 0) { r1s[wv] = a; r2s[wv] = bsum; }
    __syncthreads();
    double sd = r1s[0] + r1s[1] + r1s[2] + r1s[3];
    double sq = r2s[0] + r2s[1] + r2s[2] + r2s[3];

    const double n = (double)BB * SS * KK * 3;
    double var = (sq - sd * sd / n) / (n - 1.0);
    float stdv = (float)sqrt(var);
    float denom = __fadd_rn(stdv, 1e-5f);

    double s1 = 0.0, s2 = 0.0;
    for (int r = 0; r < 4; r++) {
        int s = r * 256 + t;
        float v;
        if (c < 3) {
            v = A[((size_t)b * SS + s) * 3 + c] / denom;
        } else {
            float ww = new_xyz[((size_t)b * SS + s) * 3 + (c - 3)];
            v = __fadd_rn(ww, ww);
        }
        lc[((size_t)b * 6 + c) * SS + s] = v;
        s1 += (double)v;
        s2 += (double)v * (double)v;
    }
#pragma unroll
    for (int off = 32; off > 0; off >>= 1) { s1 += __shfl_down(s1, off); s2 += __shfl_down(s2, off); }
    if (ln == 0) red[wv] = s1;
    __syncthreads();
    if (t == 0) atomicAdd(&bn1acc[c * 2 + 0], red[0] + red[1] + red[2] + red[3]);
    __syncthreads();
    if (ln == 0) red[wv] = s2;
    __syncthreads();
    if (t == 0) atomicAdd(&bn1acc[c * 2 + 1], red[0] + red[1] + red[2] + red[3]);
}

// ---------------------------------------------------------------------------
// K4 (FUSED cdist+bn2): per-batch BN1+cdist as before; LAST block (device
// ticket) runs bn2. Release: all threads threadfence after syncthreads,
// syncthreads, then t0's device-scope atomicAdd. Acquire: fence then read tf.
// ---------------------------------------------------------------------------
__global__ __launch_bounds__(256) void cdist_kernel(const float* __restrict__ lc,
                                                    const double* __restrict__ bn1acc,
                                                    const float* __restrict__ params,
                                                    float* __restrict__ tf,
                                                    void* __restrict__ out_raw,
                                                    int* __restrict__ cnt) {
    __shared__ float sy[6 * SS];
    __shared__ int lastf;
    const int b = blockIdx.x, t = threadIdx.x;
    float mean[6], sde[6], gg[6], bt[6];
    const double n = (double)BB * SS;
#pragma unroll
    for (int c = 0; c < 6; c++) {
        double m = bn1acc[c * 2 + 0] / n;
        double v = bn1acc[c * 2 + 1] / n - m * m;
        mean[c] = (float)m;
        sde[c] = sqrtf((float)v + 1e-5f);
        gg[c] = params[c];
        bt[c] = params[6 + c];
    }
    for (int r = 0; r < 24; r++) {
        int g = r * 256 + t;
        int c = g >> 10;
        float v = lc[(size_t)b * 6 * SS + g];
        float y = (v - mean[c]) / sde[c] * gg[c] + bt[c];
        sy[g] = fmaxf(y, 0.0f);
    }
    __syncthreads();
    if (t < 6) tf[b * 36 + t * 7] = 0.0f;

    const int w = t >> 6, lane = t & 63;
    const int PI[15] = {0,0,0,0,0,1,1,1,1,2,2,2,3,3,4};
    const int PJ[15] = {1,2,3,4,5,2,3,4,5,3,4,5,4,5,5};
    for (int r = 0; r < 4; r++) {
        int p = w + r * 4;
        if (p < 15) {
            int i = PI[p], j = PJ[p];
            float acc = 0.0f;
            for (int m2 = 0; m2 < 16; m2++) {
                int s = lane + m2 * 64;
                float d = sy[i * SS + s] - sy[j * SS + s];
                acc += d * d;
            }
#pragma unroll
            for (int off = 32; off > 0; off >>= 1) acc += __shfl_down(acc, off);
            if (lane == 0) {
                float v = acc > 0.0f ? sqrtf(acc) : 0.0f;
                const float FACTOR = 1.0f;
                tf[b * 36 + i * 6 + j] = (j == i + 1) ? v * FACTOR : v;
                tf[b * 36 + j * 6 + i] = v;
            }
        }
    }

    // ---- last-block bn2 (ticket pattern) ----
    __syncthreads();      // all tf stores issued block-wide
    __threadfence();      // each thread: device-visible flush of its stores
    __syncthreads();      // all fences complete
    if (t == 0) { lastf = (atomicAdd(cnt, 1) == BB - 1) ? 1 : 0; }
    __syncthreads();
    if (lastf) {
        __threadfence();  // acquire: other blocks' tf now visible
        if (t < 36) {
            int f = t;
            bool isbf = params[84] != 0.0f;
            float x[16]; float sum = 0.0f;
#pragma unroll
            for (int bb2 = 0; bb2 < 16; bb2++) { x[bb2] = tf[bb2 * 36 + f]; sum += x[bb2]; }
            float mean2 = sum * 0.0625f;
            float vs = 0.0f;
#pragma unroll
            for (int bb2 = 0; bb2 < 16; bb2++) { float d = x[bb2] - mean2; vs += d * d; }
            float var2 = vs * 0.0625f;
            float denom2 = sqrtf(var2 + 1e-5f);
            float g = params[12 + f], bb = params[48 + f];
#pragma unroll
            for (int bb2 = 0; bb2 < 16; bb2++) {
                float y = (x[bb2] - mean2) / denom2 * g + bb;
                y = fmaxf(y, 0.0f);
                if (isbf) ((__hip_bfloat16*)out_raw)[bb2 * 36 + f] = __float2bfloat16(y);
                else      ((float*)out_raw)[bb2 * 36 + f] = y;
            }
        }
    }
}

// ---------------------------------------------------------------------------
// Workspace layout (bytes):
//   0        : xyzf     float[16*8192*3]   (1572864)
//   1572864  : new_xyz  float[16*1024*3]   (196608)
//   1769472  : A        float[16*1024*3]   (196608)
//   1966080  : lc       float[16*6*1024]   (393216)
//   2359296  : tfcw     float[16*36]       (2304)
//   2361600  : stats    double[14]         (bn1acc = stats+2)
//   2361712  : params   float[85]          (ends 2362052)
//   2362056  : done[0]=fps finish count, done[1]=cdist ticket (zeroed/launch)
//   2362112  : qstats   double[16384*2]    (262144)
// ---------------------------------------------------------------------------
extern "C" void kernel_launch(void* const* d_in, const int* in_sizes, int n_in,
                              void* d_out, int out_size, void* d_ws, size_t ws_size,
                              hipStream_t stream) {
    const void* xyz_raw = d_in[0];
    const void* g1r = d_in[1]; const void* b1r = d_in[2];
    const void* g2r = d_in[3]; const void* b2r = d_in[4];
    {
        const void* six[2] = {nullptr, nullptr}; int n6 = 0;
        const void* t36[2] = {nullptr, nullptr}; int n36 = 0;
        const void* big = nullptr;
        for (int i = 0; i < n_in; i++) {
            if (in_sizes[i] == BB * NN * 3) big = d_in[i];
            else if (in_sizes[i] == 6  && n6  < 2) six[n6++]  = d_in[i];
            else if (in_sizes[i] == 36 && n36 < 2) t36[n36++] = d_in[i];
        }
        if (big && n6 == 2 && n36 == 2) {
            xyz_raw = big; g1r = six[0]; b1r = six[1]; g2r = t36[0]; b2r = t36[1];
        }
    }

    char* ws = (char*)d_ws;
    float* xyzf    = (float*)(ws + 0);
    float* new_xyz = (float*)(ws + 1572864);
    float* A       = (float*)(ws + 1769472);
    float* lc      = (float*)(ws + 1966080);
    float* tf      = (float*)(ws + 2359296);
    double* stats  = (double*)(ws + 2361600);
    double* bn1acc = stats + 2;
    float* params  = (float*)(ws + 2361712);
    int* done      = (int*)(ws + 2362056);
    double* qstats = (double*)(ws + 2362112);

    hipMemsetAsync(stats, 0, 14 * sizeof(double), stream);
    hipMemsetAsync(done, 0, 2 * sizeof(int), stream);
    hipLaunchKernelGGL(fps_kernel, dim3(256), dim3(512), 0, stream,
                       xyz_raw, g1r, b1r, g2r, b2r, xyzf, new_xyz, params, d_out, done);
    hipLaunchKernelGGL(knn_kernel,   dim3(4096), dim3(256), 0, stream, xyzf, new_xyz, A, qstats);
    hipLaunchKernelGGL(lc_kernel,    dim3(96),   dim3(256), 0, stream, new_xyz, A, qstats, lc, bn1acc);
    hipLaunchKernelGGL(cdist_kernel, dim3(16),   dim3(256), 0, stream, lc, bn1acc, params, tf,
                       d_out, done + 1);

    (void)in_sizes; (void)n_in; (void)out_size; (void)ws_size;
}